// Round 3
// baseline (172.559 us; speedup 1.0000x reference)
//
#include <hip/hip_runtime.h>
#include <math.h>

typedef short bf16x8 __attribute__((ext_vector_type(8)));
typedef short bf16x4 __attribute__((ext_vector_type(4)));
typedef float f32x4  __attribute__((ext_vector_type(4)));

#define INV_2PI  0.15915494309189535f
#define TWO_PI_F 6.283185307179586f
// DT/(2*pi)/N = 0.01/(2*pi)/192
#define FSCALE   8.2893199e-06f

static __device__ inline short f2bf(float f) {
    union { float f; unsigned u; } v; v.f = f;
    unsigned r = (v.u + 0x7FFFu + ((v.u >> 16) & 1u)) >> 16;
    return (short)r;
}
static __device__ inline float bf2f(short h) {
    union { unsigned u; float f; } v; v.u = ((unsigned)(unsigned short)h) << 16;
    return v.f;
}

// ============================ K1: front ============================
// [0,576):   phase split-K partials fp32. 64 rows x 64 cols x 128-K chunk,
//            BK=64 LDS tiles (row-major, coalesced staging, no transpose),
//            4 barriers total, no global stores in the K-loop.
//            partial layout: [qb=rb*4+rowq][slot][16][64] chunk-contiguous.
// [576,672): streaming converts: x fp32->bf16 into XB, W fp32->bf16 into WB
// [672,704): Kp pack (bf16 B-frag layout)
// 704:       omega/bias/bacc
__global__ __launch_bounds__(256) void front_kernel(
    const float* __restrict__ xa, const float* __restrict__ xt, const float* __restrict__ xv,
    const float* __restrict__ Wpa, const float* __restrict__ Wpt, const float* __restrict__ Wpv,
    const float* __restrict__ Wfa, const float* __restrict__ Wft, const float* __restrict__ Wfv,
    const float* __restrict__ Wfu,
    const float* __restrict__ IC,
    const float* __restrict__ oa, const float* __restrict__ ot, const float* __restrict__ ov,
    const float* __restrict__ bpa, const float* __restrict__ bpt, const float* __restrict__ bpv,
    float* __restrict__ partial, short* __restrict__ XB, short* __restrict__ WB,
    short* __restrict__ Kp,
    float* __restrict__ om_eff, float* __restrict__ bp_all, float* __restrict__ bacc)
{
    __shared__ alignas(16) float As[64][68];
    __shared__ alignas(16) float Bs[64][68];
    int b = blockIdx.x;
    int t = threadIdx.x;

    if (b < 576) {
        // ---------- phase partial ----------
        int slot = b % 18, rb = b / 18;
        int z = slot < 4 ? 0 : (slot < 10 ? 1 : 2);
        int chunk = slot - (z == 0 ? 0 : (z == 1 ? 4 : 10));
        const float* A = z == 0 ? xa : (z == 1 ? xt : xv);
        const float* W = z == 0 ? Wpa : (z == 1 ? Wpt : Wpv);
        int K = z == 0 ? 512 : (z == 1 ? 768 : 1024);
        int kb = chunk * 128;
        int m0 = rb * 64;

        int tx = t & 15, ty = t >> 4;         // compute: rows ty*4+i, cols tx*4+j
        int srow = t >> 4, sk4 = t & 15;      // staging: 16 rows/pass, float4 at k

        float acc[4][4] = {};

        // prefetch stage 0 (k offsets kb .. kb+63)
        float4 ar[4], br[4];
#pragma unroll
        for (int p = 0; p < 4; ++p) {
            ar[p] = *(const float4*)&A[(size_t)(m0 + srow + 16 * p) * K + kb + sk4 * 4];
            br[p] = *(const float4*)&W[(size_t)(srow + 16 * p) * K + kb + sk4 * 4];
        }

        for (int st = 0; st < 2; ++st) {
            if (st) __syncthreads();          // protect LDS overwrite
#pragma unroll
            for (int p = 0; p < 4; ++p) {
                *(float4*)&As[srow + 16 * p][sk4 * 4] = ar[p];
                *(float4*)&Bs[srow + 16 * p][sk4 * 4] = br[p];
            }
            __syncthreads();
            if (st == 0) {
#pragma unroll
                for (int p = 0; p < 4; ++p) {
                    ar[p] = *(const float4*)&A[(size_t)(m0 + srow + 16 * p) * K + kb + 64 + sk4 * 4];
                    br[p] = *(const float4*)&W[(size_t)(srow + 16 * p) * K + kb + 64 + sk4 * 4];
                }
            }
#pragma unroll
            for (int k4 = 0; k4 < 16; ++k4) {
                float4 a4[4], b4[4];
#pragma unroll
                for (int i = 0; i < 4; ++i) a4[i] = *(const float4*)&As[ty * 4 + i][k4 * 4];
#pragma unroll
                for (int j = 0; j < 4; ++j) b4[j] = *(const float4*)&Bs[tx * 4 + j][k4 * 4];
#pragma unroll
                for (int i = 0; i < 4; ++i)
#pragma unroll
                    for (int j = 0; j < 4; ++j) {
                        acc[i][j] += a4[i].x * b4[j].x;
                        acc[i][j] += a4[i].y * b4[j].y;
                        acc[i][j] += a4[i].z * b4[j].z;
                        acc[i][j] += a4[i].w * b4[j].w;
                    }
            }
        }

        // store: chunk-contiguous layout [qb][slot][16][64]
#pragma unroll
        for (int i = 0; i < 4; ++i) {
            int row = ty * 4 + i;
            int qb = rb * 4 + (row >> 4), rloc = row & 15;
            float4 v = make_float4(acc[i][0], acc[i][1], acc[i][2], acc[i][3]);
            *(float4*)&partial[((size_t)(qb * 18 + slot)) * 1024 + rloc * 64 + tx * 4] = v;
        }
    } else if (b < 672) {
        // ---------- streaming converts: x->XB (1179648 f4) then W->WB (196608 f4) ----------
        for (int u = (b - 576) * 256 + t; u < 1376256; u += 96 * 256) {
            if (u < 1179648) {
                const float4* sp;
                if (u < 262144)      sp = (const float4*)xa + u;
                else if (u < 655360) sp = (const float4*)xt + (u - 262144);
                else                 sp = (const float4*)xv + (u - 655360);
                float4 v = *sp;
                bf16x4 h; h[0] = f2bf(v.x); h[1] = f2bf(v.y); h[2] = f2bf(v.z); h[3] = f2bf(v.w);
                *(bf16x4*)&XB[(size_t)u * 4] = h;   // concat layout matches offsets
            } else {
                int uw = u - 1179648;
                const float4* sp;
                if (uw < 32768)       sp = (const float4*)Wfa + uw;
                else if (uw < 81920)  sp = (const float4*)Wft + (uw - 32768);
                else if (uw < 147456) sp = (const float4*)Wfv + (uw - 81920);
                else                  sp = (const float4*)Wfu + (uw - 147456);
                float4 v = *sp;
                bf16x4 h; h[0] = f2bf(v.x); h[1] = f2bf(v.y); h[2] = f2bf(v.z); h[3] = f2bf(v.w);
                *(bf16x4*)(WB + (size_t)uw * 4) = h;
            }
        }
    } else if (b < 704) {
        // ---------- Kp pack: B-frag 16x16x32 layout ----------
        for (int idx = (b - 672) * 256 + t; idx < 36864; idx += 32 * 256) {
            int k = idx / 192, n = idx - k * 192;
            float v = 0.5f * (IC[k * 192 + n] + IC[n * 192 + k]);
            int nt = n >> 4, kc = k >> 5;
            int lane = ((k >> 3) & 3) * 16 + (n & 15);
            int j = k & 7;
            Kp[((nt * 6 + kc) * 64 + lane) * 8 + j] = f2bf(v);
        }
    } else {
        if (t < 192) {
            float w = t < 64 ? oa[t] : (t < 128 ? ot[t - 64] : ov[t - 128]);
            om_eff[t] = w * (0.01f * INV_2PI);
            float bb = t < 64 ? bpa[t] : (t < 128 ? bpt[t - 64] : bpv[t - 128]);
            bp_all[t] = bb;
        }
        if (t < 4) bacc[t] = 0.f;
    }
}

// ============================ K2: kuramoto + encode ============================
// [0,128):   kuramoto (16 rows/block). Init gather = 18 coalesced b128 loads
//            per thread (chunk-contiguous partial), reduced in regs, LDS
//            redistribute. Then 10-step chain (1 barrier/step).
// [128,512): encode GEMM bf16 MFMA 64x64, BK=64; A = XB, B = WB.
__global__ __launch_bounds__(256) void mid_kernel(
    const short* __restrict__ XB, const short* __restrict__ WB,
    const float* __restrict__ ba, const float* __restrict__ bt, const float* __restrict__ bv,
    const float* __restrict__ partial, const float* __restrict__ bp_all,
    const short* __restrict__ Kp, const float* __restrict__ om_eff,
    short* __restrict__ e_bf16,
    float* __restrict__ phases_out, float* __restrict__ pm, float* __restrict__ bacc)
{
    __shared__ alignas(16) char smem[27840];
    int b = blockIdx.x;
    int t = threadIdx.x;
    int lane = t & 63, w = t >> 6;
    int q = lane >> 4, col = lane & 15;

    if (b >= 128) {
        // ---------- encode ----------
        int bb = b - 128;
        int z = bb / 128, r = bb % 128;
        int m0 = (r >> 2) * 64, n0 = (r & 3) * 64;
        const short* A    = XB + (z == 0 ? 0 : (z == 1 ? 1048576 : 2621440));
        const short* W    = WB + (z == 0 ? 0 : (z == 1 ? 131072 : 327680));
        const float* bias = z == 0 ? ba : (z == 1 ? bt : bv);
        int K             = z == 0 ? 512 : (z == 1 ? 768 : 1024);

        short* As = (short*)smem;            // [64][72]
        short* Bs = (short*)smem + 64 * 72;

        int srow = t >> 3, sc8 = t & 7;      // staging: 32 rows x 8 groups per pass

        f32x4 acc[4];
#pragma unroll
        for (int f = 0; f < 4; ++f)
#pragma unroll
            for (int rr = 0; rr < 4; ++rr) acc[f][rr] = 0.f;

        bf16x8 av[2], bv8[2];
#pragma unroll
        for (int p = 0; p < 2; ++p) {
            av[p]  = *(const bf16x8*)&A[(size_t)(m0 + srow + 32 * p) * K + sc8 * 8];
            bv8[p] = *(const bf16x8*)&W[(size_t)(n0 + srow + 32 * p) * K + sc8 * 8];
        }

        for (int kb = 0; kb < K; kb += 64) {
            if (kb) __syncthreads();
#pragma unroll
            for (int p = 0; p < 2; ++p) {
                *(bf16x8*)&As[(srow + 32 * p) * 72 + sc8 * 8] = av[p];
                *(bf16x8*)&Bs[(srow + 32 * p) * 72 + sc8 * 8] = bv8[p];
            }
            __syncthreads();
            if (kb + 64 < K) {
#pragma unroll
                for (int p = 0; p < 2; ++p) {
                    av[p]  = *(const bf16x8*)&A[(size_t)(m0 + srow + 32 * p) * K + kb + 64 + sc8 * 8];
                    bv8[p] = *(const bf16x8*)&W[(size_t)(n0 + srow + 32 * p) * K + kb + 64 + sc8 * 8];
                }
            }

            bf16x8 bfr[2];
#pragma unroll
            for (int kc = 0; kc < 2; ++kc)
                bfr[kc] = *(const bf16x8*)&Bs[(w * 16 + col) * 72 + kc * 32 + q * 8];
#pragma unroll
            for (int f = 0; f < 4; ++f)
#pragma unroll
                for (int kc = 0; kc < 2; ++kc) {
                    bf16x8 af = *(const bf16x8*)&As[(f * 16 + col) * 72 + kc * 32 + q * 8];
                    acc[f] = __builtin_amdgcn_mfma_f32_16x16x32_bf16(af, bfr[kc], acc[f], 0, 0, 0);
                }
        }

        int n = n0 + w * 16 + col;
        float bn = bias[n];
#pragma unroll
        for (int f = 0; f < 4; ++f)
#pragma unroll
            for (int rr = 0; rr < 4; ++rr) {
                int m = m0 + f * 16 + q * 4 + rr;
                e_bf16[(size_t)m * 768 + z * 256 + n] = f2bf(acc[f][rr] + bn);
            }
    } else {
        // ---------- kuramoto ----------
        short (*cs)[2][16][216] = (short (*)[2][16][216])smem;      // 27648 B
        float (*Rl)[3] = (float (*)[3])(smem + 27648);              // 192 B
        float* ph0 = (float*)smem;                                  // [16][196] (pre-step scratch)

        int m0 = b * 16;

        bf16x8 kb[3][6];
#pragma unroll
        for (int ntl = 0; ntl < 3; ++ntl)
#pragma unroll
            for (int kc = 0; kc < 6; ++kc) {
                int nt = w * 3 + ntl;
                kb[ntl][kc] = *(const bf16x8*)&Kp[((nt * 6 + kc) * 64 + lane) * 8];
            }

        // ---- init gather: 18 coalesced b128 loads, reduce per modality ----
        {
            const float* Pb = partial + (size_t)b * 18 * 1024;
            f32x4 s0, s1, s2;
#pragma unroll
            for (int j = 0; j < 4; ++j) { s0[j] = 0.f; s1[j] = 0.f; s2[j] = 0.f; }
#pragma unroll
            for (int s = 0; s < 18; ++s) {
                f32x4 v = *(const f32x4*)&Pb[s * 1024 + t * 4];
                if (s < 4)       s0 += v;
                else if (s < 10) s1 += v;
                else             s2 += v;
            }
            int row = t >> 4, c4 = t & 15;
            *(f32x4*)&ph0[row * 196 +   0 + c4 * 4] = s0;
            *(f32x4*)&ph0[row * 196 +  64 + c4 * 4] = s1;
            *(f32x4*)&ph0[row * 196 + 128 + c4 * 4] = s2;
        }
        __syncthreads();

        float ph[3][4], om[3], c[3][4], s[3][4];
#pragma unroll
        for (int ntl = 0; ntl < 3; ++ntl) {
            int i = (w * 3 + ntl) * 16 + col;
            om[ntl] = om_eff[i];
#pragma unroll
            for (int r = 0; r < 4; ++r) {
                float raw = bp_all[i] + ph0[(q * 4 + r) * 196 + i];
                raw *= INV_2PI;
                ph[ntl][r] = raw - floorf(raw);
            }
        }
        __syncthreads();   // ph0 region reused as cs below

        for (int step = 0; step < 10; ++step) {
            int p = step & 1;
#pragma unroll
            for (int ntl = 0; ntl < 3; ++ntl) {
                int i = (w * 3 + ntl) * 16 + col;
#pragma unroll
                for (int r = 0; r < 4; ++r) {
                    c[ntl][r] = __builtin_amdgcn_cosf(ph[ntl][r]);  // v_cos_f32: revolutions
                    s[ntl][r] = __builtin_amdgcn_sinf(ph[ntl][r]);
                    cs[p][0][q * 4 + r][i] = f2bf(c[ntl][r]);
                    cs[p][1][q * 4 + r][i] = f2bf(s[ntl][r]);
                }
            }
            __syncthreads();
            // (2nd per-step barrier elided: cs double-buffered)

            f32x4 aC[3], aS[3];
#pragma unroll
            for (int ntl = 0; ntl < 3; ++ntl)
#pragma unroll
                for (int r = 0; r < 4; ++r) { aC[ntl][r] = 0.f; aS[ntl][r] = 0.f; }

#pragma unroll
            for (int kc = 0; kc < 6; ++kc) {
                bf16x8 ac  = *(const bf16x8*)&cs[p][0][col][kc * 32 + q * 8];
                bf16x8 as_ = *(const bf16x8*)&cs[p][1][col][kc * 32 + q * 8];
#pragma unroll
                for (int ntl = 0; ntl < 3; ++ntl) {
                    aC[ntl] = __builtin_amdgcn_mfma_f32_16x16x32_bf16(ac,  kb[ntl][kc], aC[ntl], 0, 0, 0);
                    aS[ntl] = __builtin_amdgcn_mfma_f32_16x16x32_bf16(as_, kb[ntl][kc], aS[ntl], 0, 0, 0);
                }
            }

#pragma unroll
            for (int ntl = 0; ntl < 3; ++ntl)
#pragma unroll
                for (int r = 0; r < 4; ++r) {
                    float f = (s[ntl][r] * aC[ntl][r] - c[ntl][r] * aS[ntl][r]) * FSCALE;
                    float pn = ph[ntl][r] + om[ntl] + f;
                    ph[ntl][r] = pn - floorf(pn);
                }
        }

#pragma unroll
        for (int ntl = 0; ntl < 3; ++ntl) {
            int i = (w * 3 + ntl) * 16 + col;
#pragma unroll
            for (int r = 0; r < 4; ++r) {
                float cp = __builtin_amdgcn_cosf(ph[ntl][r]);
                float sp = __builtin_amdgcn_sinf(ph[ntl][r]);
                cs[0][0][q * 4 + r][i] = f2bf(cp);
                cs[0][1][q * 4 + r][i] = f2bf(sp);
                phases_out[(size_t)(m0 + q * 4 + r) * 192 + i] = ph[ntl][r] * TWO_PI_F;
            }
        }
        __syncthreads();

        if (t < 48) {
            int r = t & 15, mod = t >> 4;
            float sc = 0.f, ss = 0.f;
#pragma unroll
            for (int g = 0; g < 8; ++g) {
                bf16x8 vc = *(const bf16x8*)&cs[0][0][r][mod * 64 + g * 8];
                bf16x8 vs = *(const bf16x8*)&cs[0][1][r][mod * 64 + g * 8];
#pragma unroll
                for (int j = 0; j < 8; ++j) { sc += bf2f(vc[j]); ss += bf2f(vs[j]); }
            }
            sc *= (1.f / 64.f); ss *= (1.f / 64.f);
            pm[(size_t)(m0 + r) * 3 + mod] = 0.5f + 0.5f * sc;
            Rl[r][mod] = sqrtf(sc * sc + ss * ss);
        }
        __syncthreads();
        if (t < 3) {
            int a = (t == 2) ? 1 : 0;
            int bb = (t == 0) ? 1 : 2;
            float accp = 0.f;
            for (int r = 0; r < 16; ++r) accp += Rl[r][a] * Rl[r][bb];
            atomicAdd(&bacc[t], accp);
        }
    }
}

// ============================ K3: fusion + finalize ============================
// bound = (e * pm_scale) @ Wfu^T + b_fusion. Grid (128,2): 16 rows x 128 cols
// per block. Full scaled A row-block staged in LDS once (1 barrier), then a
// barrier-free K-loop with reg-double-buffered B frags from L2/L3.
__global__ __launch_bounds__(256) void back_kernel(
    const short* __restrict__ e_bf16, const short* __restrict__ WB,
    const float* __restrict__ bias, const float* __restrict__ pm,
    const float* __restrict__ bacc,
    float* __restrict__ out_bound, float* __restrict__ out_bm, float* __restrict__ out_total)
{
    const short* Wfb = WB + 589824;   // Wfu slab (bf16)
    __shared__ alignas(16) short As2[16 * 776];   // 24832 B

    int m0 = blockIdx.x * 16, n0 = blockIdx.y * 128;
    int t = threadIdx.x;
    int lane = t & 63, w = t >> 6;
    int q = lane >> 4, col = lane & 15;

#pragma unroll
    for (int i = 0; i < 6; ++i) {
        int g = t + 256 * i;                 // < 1536
        int rw = g / 96, cg = g - rw * 96;
        float sc = pm[(size_t)(m0 + rw) * 3 + (cg >> 5)];
        bf16x8 v = *(const bf16x8*)&e_bf16[(size_t)(m0 + rw) * 768 + cg * 8];
        bf16x8 h;
#pragma unroll
        for (int j = 0; j < 8; ++j) h[j] = f2bf(bf2f(v[j]) * sc);
        *(bf16x8*)&As2[rw * 776 + cg * 8] = h;
    }
    __syncthreads();

    f32x4 facc[2];
#pragma unroll
    for (int j = 0; j < 2; ++j)
#pragma unroll
        for (int rr = 0; rr < 4; ++rr) facc[j][rr] = 0.f;

    int n_[2];
#pragma unroll
    for (int j = 0; j < 2; ++j) n_[j] = n0 + (w * 2 + j) * 16 + col;

    bf16x8 bcur[2], bnxt[2];
#pragma unroll
    for (int j = 0; j < 2; ++j)
        bcur[j] = *(const bf16x8*)&Wfb[(size_t)n_[j] * 768 + q * 8];

    for (int k0 = 0; k0 < 768; k0 += 32) {
        if (k0 + 32 < 768) {
#pragma unroll
            for (int j = 0; j < 2; ++j)
                bnxt[j] = *(const bf16x8*)&Wfb[(size_t)n_[j] * 768 + k0 + 32 + q * 8];
        }
        bf16x8 af = *(const bf16x8*)&As2[col * 776 + k0 + q * 8];
#pragma unroll
        for (int j = 0; j < 2; ++j)
            facc[j] = __builtin_amdgcn_mfma_f32_16x16x32_bf16(af, bcur[j], facc[j], 0, 0, 0);
#pragma unroll
        for (int j = 0; j < 2; ++j) bcur[j] = bnxt[j];
    }

#pragma unroll
    for (int j = 0; j < 2; ++j) {
        float bn = bias[n_[j]];
#pragma unroll
        for (int rr = 0; rr < 4; ++rr) {
            int m = m0 + q * 4 + rr;
            out_bound[(size_t)m * 256 + n_[j]] = facc[j][rr] + bn;
        }
    }

    if (blockIdx.x == 0 && blockIdx.y == 0) {
        float p01 = bacc[0] * (1.f / 2048.f);
        float p02 = bacc[1] * (1.f / 2048.f);
        float p12 = bacc[2] * (1.f / 2048.f);
        float total = (p01 + p02 + p12) * (1.f / 3.f);
        if (t == 0) {
            out_bm[0] = 1.f; out_bm[1] = p01; out_bm[2] = p02;
            out_bm[3] = p01; out_bm[4] = 1.f; out_bm[5] = p12;
            out_bm[6] = p02; out_bm[7] = p12; out_bm[8] = 1.f;
        }
        for (int i = t; i < 2048; i += 256) out_total[i] = total;
    }
}

// ============================ launch ============================
extern "C" void kernel_launch(void* const* d_in, const int* in_sizes, int n_in,
                              void* d_out, int out_size, void* d_ws, size_t ws_size,
                              hipStream_t stream)
{
    const float* x_a  = (const float*)d_in[0];
    const float* Wf_a = (const float*)d_in[1];
    const float* bf_a = (const float*)d_in[2];
    const float* Wp_a = (const float*)d_in[3];
    const float* bp_a = (const float*)d_in[4];
    const float* x_t  = (const float*)d_in[5];
    const float* Wf_t = (const float*)d_in[6];
    const float* bf_t = (const float*)d_in[7];
    const float* Wp_t = (const float*)d_in[8];
    const float* bp_t = (const float*)d_in[9];
    const float* x_v  = (const float*)d_in[10];
    const float* Wf_v = (const float*)d_in[11];
    const float* bf_v = (const float*)d_in[12];
    const float* Wp_v = (const float*)d_in[13];
    const float* bp_v = (const float*)d_in[14];
    const float* om_a = (const float*)d_in[15];
    const float* om_t = (const float*)d_in[16];
    const float* om_v = (const float*)d_in[17];
    const float* IC   = (const float*)d_in[18];
    const float* Wfu  = (const float*)d_in[19];
    const float* bfu  = (const float*)d_in[20];

    float* ws      = (float*)d_ws;
    float* omw     = ws;                        // 256
    float* bpw     = ws + 256;                  // 256
    float* pmv     = ws + 512;                  // 6144
    float* baccw   = ws + 6656;                 // 64
    float* partial = ws + 6720;                 // 128*18*1024 = 2359296
    short* e_bf    = (short*)(ws + 2366016);    // 1572864 shorts
    short* XB      = (short*)(ws + 3152448);    // 4718592 shorts
    short* Kpck    = (short*)(ws + 5511744);    // 36864 shorts
    short* WB      = (short*)(ws + 5530176);    // 786432 shorts

    float* out        = (float*)d_out;
    float* out_bound  = out;           // 2048*256
    float* out_bm     = out + 524288;  // 9
    float* out_phases = out + 524297;  // 2048*192
    float* out_total  = out + 917513;  // 2048

    front_kernel<<<705, 256, 0, stream>>>(
        x_a, x_t, x_v, Wp_a, Wp_t, Wp_v, Wf_a, Wf_t, Wf_v, Wfu,
        IC, om_a, om_t, om_v, bp_a, bp_t, bp_v,
        partial, XB, WB, Kpck, omw, bpw, baccw);

    mid_kernel<<<512, 256, 0, stream>>>(
        XB, WB, bf_a, bf_t, bf_v,
        partial, bpw, Kpck, omw,
        e_bf, out_phases, pmv, baccw);

    dim3 gF(128, 2);
    back_kernel<<<gF, 256, 0, stream>>>(e_bf, WB, bfu, pmv, baccw,
                                        out_bound, out_bm, out_total);
}

// Round 4
// 142.308 us; speedup vs baseline: 1.2126x; 1.2126x over previous
//
#include <hip/hip_runtime.h>
#include <math.h>

typedef short bf16x8 __attribute__((ext_vector_type(8)));
typedef short bf16x4 __attribute__((ext_vector_type(4)));
typedef float f32x4  __attribute__((ext_vector_type(4)));

#define INV_2PI  0.15915494309189535f
#define TWO_PI_F 6.283185307179586f
// DT/(2*pi)/N = 0.01/(2*pi)/192
#define FSCALE   8.2893199e-06f

static __device__ inline short f2bf(float f) {
    union { float f; unsigned u; } v; v.f = f;
    unsigned r = (v.u + 0x7FFFu + ((v.u >> 16) & 1u)) >> 16;
    return (short)r;
}
static __device__ inline float bf2f(short h) {
    union { unsigned u; float f; } v; v.u = ((unsigned)(unsigned short)h) << 16;
    return v.f;
}

// ============================ K1: front ============================
// [0,576):   phase split-K partials fp32 (64 rows x 64 cols x 128-K chunk,
//            18 slots x 32 row-blocks), transposed [16][72] LDS (conflict-free
//            column reads), reg double-buffered; FUSED bf16(x) emit into XB.
//            partial store: chunk-contiguous [qb][slot][16][64] for mid's
//            coalesced gather. MAC order identical to the verified R2 kernel.
// [576,600): Wf a|t|v + Wfu fp32->bf16 convert into WB concat
// [600,632): Kp pack (bf16 B-frag layout)
// 632:       omega/bias/bacc
__global__ __launch_bounds__(256) void front_kernel(
    const float* __restrict__ xa, const float* __restrict__ xt, const float* __restrict__ xv,
    const float* __restrict__ Wpa, const float* __restrict__ Wpt, const float* __restrict__ Wpv,
    const float* __restrict__ Wfa, const float* __restrict__ Wft, const float* __restrict__ Wfv,
    const float* __restrict__ Wfu,
    const float* __restrict__ IC,
    const float* __restrict__ oa, const float* __restrict__ ot, const float* __restrict__ ov,
    const float* __restrict__ bpa, const float* __restrict__ bpt, const float* __restrict__ bpv,
    float* __restrict__ partial, short* __restrict__ XB, short* __restrict__ WB,
    short* __restrict__ Kp,
    float* __restrict__ om_eff, float* __restrict__ bp_all, float* __restrict__ bacc)
{
    __shared__ alignas(16) float As[16][72];
    __shared__ alignas(16) float Bs[16][72];
    int b = blockIdx.x;
    int t = threadIdx.x;

    if (b < 576) {
        // ---------- phase partial + fused x->bf16 ----------
        int slot = b % 18, rb = b / 18;
        int z = slot < 4 ? 0 : (slot < 10 ? 1 : 2);
        int chunk = slot - (z == 0 ? 0 : (z == 1 ? 4 : 10));
        const float* A = z == 0 ? xa : (z == 1 ? xt : xv);
        const float* W = z == 0 ? Wpa : (z == 1 ? Wpt : Wpv);
        short* XBz = XB + (z == 0 ? 0 : (z == 1 ? 1048576 : 2621440));
        int K = z == 0 ? 512 : (z == 1 ? 768 : 1024);
        int kb = chunk * 128;
        int m0 = rb * 64;

        int tx = t & 15, ty = t >> 4;
        int row = t >> 2, c4 = t & 3;

        float acc[4][4] = {};
        // prefetch regs for k0 = 0
        float4 ar = *(const float4*)&A[(size_t)(m0 + row) * K + kb + c4 * 4];
        float4 br = *(const float4*)&W[(size_t)row * K + kb + c4 * 4];

        for (int k0 = 0; k0 < 128; k0 += 16) {
            if (k0) __syncthreads();          // LDS free (prev compute done)
            As[c4 * 4 + 0][row] = ar.x;
            As[c4 * 4 + 1][row] = ar.y;
            As[c4 * 4 + 2][row] = ar.z;
            As[c4 * 4 + 3][row] = ar.w;
            Bs[c4 * 4 + 0][row] = br.x;
            Bs[c4 * 4 + 1][row] = br.y;
            Bs[c4 * 4 + 2][row] = br.z;
            Bs[c4 * 4 + 3][row] = br.w;
            // fused bf16 emit of this block's exclusive x-tile (data already here)
            {
                bf16x4 h; h[0] = f2bf(ar.x); h[1] = f2bf(ar.y);
                h[2] = f2bf(ar.z); h[3] = f2bf(ar.w);
                *(bf16x4*)&XBz[(size_t)(m0 + row) * K + kb + k0 + c4 * 4] = h;
            }
            __syncthreads();
            if (k0 + 16 < 128) {              // issue next loads before compute
                ar = *(const float4*)&A[(size_t)(m0 + row) * K + kb + k0 + 16 + c4 * 4];
                br = *(const float4*)&W[(size_t)row * K + kb + k0 + 16 + c4 * 4];
            }
#pragma unroll
            for (int kk = 0; kk < 16; ++kk) {
                float4 aq = *(const float4*)&As[kk][ty * 4];
                float4 bq = *(const float4*)&Bs[kk][tx * 4];
                float av[4] = {aq.x, aq.y, aq.z, aq.w};
                float bv[4] = {bq.x, bq.y, bq.z, bq.w};
#pragma unroll
                for (int i = 0; i < 4; ++i)
#pragma unroll
                    for (int j = 0; j < 4; ++j)
                        acc[i][j] += av[i] * bv[j];
            }
        }

        // store: chunk-contiguous layout [qb][slot][16][64]
#pragma unroll
        for (int i = 0; i < 4; ++i) {
            int row_l = ty * 4 + i;
            int qb = rb * 4 + (row_l >> 4), rloc = row_l & 15;
            float4 v = make_float4(acc[i][0], acc[i][1], acc[i][2], acc[i][3]);
            *(float4*)&partial[((size_t)(qb * 18 + slot)) * 1024 + rloc * 64 + tx * 4] = v;
        }
    } else if (b < 600) {
        // ---------- W fp32->bf16 convert (f4 units; Wfa|Wft|Wfv|Wfu concat) ----------
        for (int u = (b - 576) * 256 + t; u < 196608; u += 24 * 256) {
            const float4* sp;
            if (u < 32768)       sp = (const float4*)Wfa + u;
            else if (u < 81920)  sp = (const float4*)Wft + (u - 32768);
            else if (u < 147456) sp = (const float4*)Wfv + (u - 81920);
            else                 sp = (const float4*)Wfu + (u - 147456);
            float4 v = *sp;
            bf16x4 h; h[0] = f2bf(v.x); h[1] = f2bf(v.y); h[2] = f2bf(v.z); h[3] = f2bf(v.w);
            *(bf16x4*)(WB + (size_t)u * 4) = h;
        }
    } else if (b < 632) {
        // ---------- Kp pack: B-frag 16x16x32 layout ----------
        for (int idx = (b - 600) * 256 + t; idx < 36864; idx += 32 * 256) {
            int k = idx / 192, n = idx - k * 192;
            float v = 0.5f * (IC[k * 192 + n] + IC[n * 192 + k]);
            int nt = n >> 4, kc = k >> 5;
            int lane = ((k >> 3) & 3) * 16 + (n & 15);
            int j = k & 7;
            Kp[((nt * 6 + kc) * 64 + lane) * 8 + j] = f2bf(v);
        }
    } else {
        if (t < 192) {
            float w = t < 64 ? oa[t] : (t < 128 ? ot[t - 64] : ov[t - 128]);
            om_eff[t] = w * (0.01f * INV_2PI);
            float bb = t < 64 ? bpa[t] : (t < 128 ? bpt[t - 64] : bpv[t - 128]);
            bp_all[t] = bb;
        }
        if (t < 4) bacc[t] = 0.f;
    }
}

// ============================ K2: kuramoto + encode ============================
// [0,128):   kuramoto (16 rows/block). Init gather = 18 coalesced b128 loads
//            per thread (chunk-contiguous partial), reduced in regs, LDS
//            redistribute. Then 10-step chain (1 barrier/step).
// [128,512): encode GEMM bf16 MFMA 64x64, BK=64; A = XB, B = WB.
__global__ __launch_bounds__(256) void mid_kernel(
    const short* __restrict__ XB, const short* __restrict__ WB,
    const float* __restrict__ ba, const float* __restrict__ bt, const float* __restrict__ bv,
    const float* __restrict__ partial, const float* __restrict__ bp_all,
    const short* __restrict__ Kp, const float* __restrict__ om_eff,
    short* __restrict__ e_bf16,
    float* __restrict__ phases_out, float* __restrict__ pm, float* __restrict__ bacc)
{
    __shared__ alignas(16) char smem[27840];
    int b = blockIdx.x;
    int t = threadIdx.x;
    int lane = t & 63, w = t >> 6;
    int q = lane >> 4, col = lane & 15;

    if (b >= 128) {
        // ---------- encode ----------
        int bb = b - 128;
        int z = bb / 128, r = bb % 128;
        int m0 = (r >> 2) * 64, n0 = (r & 3) * 64;
        const short* A    = XB + (z == 0 ? 0 : (z == 1 ? 1048576 : 2621440));
        const short* W    = WB + (z == 0 ? 0 : (z == 1 ? 131072 : 327680));
        const float* bias = z == 0 ? ba : (z == 1 ? bt : bv);
        int K             = z == 0 ? 512 : (z == 1 ? 768 : 1024);

        short* As = (short*)smem;            // [64][72]
        short* Bs = (short*)smem + 64 * 72;

        int srow = t >> 3, sc8 = t & 7;      // staging: 32 rows x 8 groups per pass

        f32x4 acc[4];
#pragma unroll
        for (int f = 0; f < 4; ++f)
#pragma unroll
            for (int rr = 0; rr < 4; ++rr) acc[f][rr] = 0.f;

        bf16x8 av[2], bv8[2];
#pragma unroll
        for (int p = 0; p < 2; ++p) {
            av[p]  = *(const bf16x8*)&A[(size_t)(m0 + srow + 32 * p) * K + sc8 * 8];
            bv8[p] = *(const bf16x8*)&W[(size_t)(n0 + srow + 32 * p) * K + sc8 * 8];
        }

        for (int kb = 0; kb < K; kb += 64) {
            if (kb) __syncthreads();
#pragma unroll
            for (int p = 0; p < 2; ++p) {
                *(bf16x8*)&As[(srow + 32 * p) * 72 + sc8 * 8] = av[p];
                *(bf16x8*)&Bs[(srow + 32 * p) * 72 + sc8 * 8] = bv8[p];
            }
            __syncthreads();
            if (kb + 64 < K) {
#pragma unroll
                for (int p = 0; p < 2; ++p) {
                    av[p]  = *(const bf16x8*)&A[(size_t)(m0 + srow + 32 * p) * K + kb + 64 + sc8 * 8];
                    bv8[p] = *(const bf16x8*)&W[(size_t)(n0 + srow + 32 * p) * K + kb + 64 + sc8 * 8];
                }
            }

            bf16x8 bfr[2];
#pragma unroll
            for (int kc = 0; kc < 2; ++kc)
                bfr[kc] = *(const bf16x8*)&Bs[(w * 16 + col) * 72 + kc * 32 + q * 8];
#pragma unroll
            for (int f = 0; f < 4; ++f)
#pragma unroll
                for (int kc = 0; kc < 2; ++kc) {
                    bf16x8 af = *(const bf16x8*)&As[(f * 16 + col) * 72 + kc * 32 + q * 8];
                    acc[f] = __builtin_amdgcn_mfma_f32_16x16x32_bf16(af, bfr[kc], acc[f], 0, 0, 0);
                }
        }

        int n = n0 + w * 16 + col;
        float bn = bias[n];
#pragma unroll
        for (int f = 0; f < 4; ++f)
#pragma unroll
            for (int rr = 0; rr < 4; ++rr) {
                int m = m0 + f * 16 + q * 4 + rr;
                e_bf16[(size_t)m * 768 + z * 256 + n] = f2bf(acc[f][rr] + bn);
            }
    } else {
        // ---------- kuramoto ----------
        short (*cs)[2][16][216] = (short (*)[2][16][216])smem;      // 27648 B
        float (*Rl)[3] = (float (*)[3])(smem + 27648);              // 192 B
        float* ph0 = (float*)smem;                                  // [16][196] (pre-step scratch)

        int m0 = b * 16;

        bf16x8 kb[3][6];
#pragma unroll
        for (int ntl = 0; ntl < 3; ++ntl)
#pragma unroll
            for (int kc = 0; kc < 6; ++kc) {
                int nt = w * 3 + ntl;
                kb[ntl][kc] = *(const bf16x8*)&Kp[((nt * 6 + kc) * 64 + lane) * 8];
            }

        // ---- init gather: 18 coalesced b128 loads, reduce per modality ----
        {
            const float* Pb = partial + (size_t)b * 18 * 1024;
            f32x4 s0, s1, s2;
#pragma unroll
            for (int j = 0; j < 4; ++j) { s0[j] = 0.f; s1[j] = 0.f; s2[j] = 0.f; }
#pragma unroll
            for (int s = 0; s < 18; ++s) {
                f32x4 v = *(const f32x4*)&Pb[s * 1024 + t * 4];
                if (s < 4)       s0 += v;
                else if (s < 10) s1 += v;
                else             s2 += v;
            }
            int row = t >> 4, c4 = t & 15;
            *(f32x4*)&ph0[row * 196 +   0 + c4 * 4] = s0;
            *(f32x4*)&ph0[row * 196 +  64 + c4 * 4] = s1;
            *(f32x4*)&ph0[row * 196 + 128 + c4 * 4] = s2;
        }
        __syncthreads();

        float ph[3][4], om[3], c[3][4], s[3][4];
#pragma unroll
        for (int ntl = 0; ntl < 3; ++ntl) {
            int i = (w * 3 + ntl) * 16 + col;
            om[ntl] = om_eff[i];
#pragma unroll
            for (int r = 0; r < 4; ++r) {
                float raw = bp_all[i] + ph0[(q * 4 + r) * 196 + i];
                raw *= INV_2PI;
                ph[ntl][r] = raw - floorf(raw);
            }
        }
        __syncthreads();   // ph0 region reused as cs below

        for (int step = 0; step < 10; ++step) {
            int p = step & 1;
#pragma unroll
            for (int ntl = 0; ntl < 3; ++ntl) {
                int i = (w * 3 + ntl) * 16 + col;
#pragma unroll
                for (int r = 0; r < 4; ++r) {
                    c[ntl][r] = __builtin_amdgcn_cosf(ph[ntl][r]);  // v_cos_f32: revolutions
                    s[ntl][r] = __builtin_amdgcn_sinf(ph[ntl][r]);
                    cs[p][0][q * 4 + r][i] = f2bf(c[ntl][r]);
                    cs[p][1][q * 4 + r][i] = f2bf(s[ntl][r]);
                }
            }
            __syncthreads();
            // (2nd per-step barrier elided: cs double-buffered)

            f32x4 aC[3], aS[3];
#pragma unroll
            for (int ntl = 0; ntl < 3; ++ntl)
#pragma unroll
                for (int r = 0; r < 4; ++r) { aC[ntl][r] = 0.f; aS[ntl][r] = 0.f; }

#pragma unroll
            for (int kc = 0; kc < 6; ++kc) {
                bf16x8 ac  = *(const bf16x8*)&cs[p][0][col][kc * 32 + q * 8];
                bf16x8 as_ = *(const bf16x8*)&cs[p][1][col][kc * 32 + q * 8];
#pragma unroll
                for (int ntl = 0; ntl < 3; ++ntl) {
                    aC[ntl] = __builtin_amdgcn_mfma_f32_16x16x32_bf16(ac,  kb[ntl][kc], aC[ntl], 0, 0, 0);
                    aS[ntl] = __builtin_amdgcn_mfma_f32_16x16x32_bf16(as_, kb[ntl][kc], aS[ntl], 0, 0, 0);
                }
            }

#pragma unroll
            for (int ntl = 0; ntl < 3; ++ntl)
#pragma unroll
                for (int r = 0; r < 4; ++r) {
                    float f = (s[ntl][r] * aC[ntl][r] - c[ntl][r] * aS[ntl][r]) * FSCALE;
                    float pn = ph[ntl][r] + om[ntl] + f;
                    ph[ntl][r] = pn - floorf(pn);
                }
        }

#pragma unroll
        for (int ntl = 0; ntl < 3; ++ntl) {
            int i = (w * 3 + ntl) * 16 + col;
#pragma unroll
            for (int r = 0; r < 4; ++r) {
                float cp = __builtin_amdgcn_cosf(ph[ntl][r]);
                float sp = __builtin_amdgcn_sinf(ph[ntl][r]);
                cs[0][0][q * 4 + r][i] = f2bf(cp);
                cs[0][1][q * 4 + r][i] = f2bf(sp);
                phases_out[(size_t)(m0 + q * 4 + r) * 192 + i] = ph[ntl][r] * TWO_PI_F;
            }
        }
        __syncthreads();

        if (t < 48) {
            int r = t & 15, mod = t >> 4;
            float sc = 0.f, ss = 0.f;
#pragma unroll
            for (int g = 0; g < 8; ++g) {
                bf16x8 vc = *(const bf16x8*)&cs[0][0][r][mod * 64 + g * 8];
                bf16x8 vs = *(const bf16x8*)&cs[0][1][r][mod * 64 + g * 8];
#pragma unroll
                for (int j = 0; j < 8; ++j) { sc += bf2f(vc[j]); ss += bf2f(vs[j]); }
            }
            sc *= (1.f / 64.f); ss *= (1.f / 64.f);
            pm[(size_t)(m0 + r) * 3 + mod] = 0.5f + 0.5f * sc;
            Rl[r][mod] = sqrtf(sc * sc + ss * ss);
        }
        __syncthreads();
        if (t < 3) {
            int a = (t == 2) ? 1 : 0;
            int bb = (t == 0) ? 1 : 2;
            float accp = 0.f;
            for (int r = 0; r < 16; ++r) accp += Rl[r][a] * Rl[r][bb];
            atomicAdd(&bacc[t], accp);
        }
    }
}

// ============================ K3: fusion + finalize ============================
// bound = (e * pm_scale) @ Wfu^T + b_fusion. Grid (128,2): 16 rows x 128 cols
// per block. Full scaled A row-block staged in LDS once (1 barrier), then a
// barrier-free K-loop with reg-double-buffered B frags from L2/L3.
__global__ __launch_bounds__(256) void back_kernel(
    const short* __restrict__ e_bf16, const short* __restrict__ WB,
    const float* __restrict__ bias, const float* __restrict__ pm,
    const float* __restrict__ bacc,
    float* __restrict__ out_bound, float* __restrict__ out_bm, float* __restrict__ out_total)
{
    const short* Wfb = WB + 589824;   // Wfu slab (bf16)
    __shared__ alignas(16) short As2[16 * 776];   // 24832 B

    int m0 = blockIdx.x * 16, n0 = blockIdx.y * 128;
    int t = threadIdx.x;
    int lane = t & 63, w = t >> 6;
    int q = lane >> 4, col = lane & 15;

#pragma unroll
    for (int i = 0; i < 6; ++i) {
        int g = t + 256 * i;                 // < 1536
        int rw = g / 96, cg = g - rw * 96;
        float sc = pm[(size_t)(m0 + rw) * 3 + (cg >> 5)];
        bf16x8 v = *(const bf16x8*)&e_bf16[(size_t)(m0 + rw) * 768 + cg * 8];
        bf16x8 h;
#pragma unroll
        for (int j = 0; j < 8; ++j) h[j] = f2bf(bf2f(v[j]) * sc);
        *(bf16x8*)&As2[rw * 776 + cg * 8] = h;
    }
    __syncthreads();

    f32x4 facc[2];
#pragma unroll
    for (int j = 0; j < 2; ++j)
#pragma unroll
        for (int rr = 0; rr < 4; ++rr) facc[j][rr] = 0.f;

    int n_[2];
#pragma unroll
    for (int j = 0; j < 2; ++j) n_[j] = n0 + (w * 2 + j) * 16 + col;

    bf16x8 bcur[2], bnxt[2];
#pragma unroll
    for (int j = 0; j < 2; ++j)
        bcur[j] = *(const bf16x8*)&Wfb[(size_t)n_[j] * 768 + q * 8];

    for (int k0 = 0; k0 < 768; k0 += 32) {
        if (k0 + 32 < 768) {
#pragma unroll
            for (int j = 0; j < 2; ++j)
                bnxt[j] = *(const bf16x8*)&Wfb[(size_t)n_[j] * 768 + k0 + 32 + q * 8];
        }
        bf16x8 af = *(const bf16x8*)&As2[col * 776 + k0 + q * 8];
#pragma unroll
        for (int j = 0; j < 2; ++j)
            facc[j] = __builtin_amdgcn_mfma_f32_16x16x32_bf16(af, bcur[j], facc[j], 0, 0, 0);
#pragma unroll
        for (int j = 0; j < 2; ++j) bcur[j] = bnxt[j];
    }

#pragma unroll
    for (int j = 0; j < 2; ++j) {
        float bn = bias[n_[j]];
#pragma unroll
        for (int rr = 0; rr < 4; ++rr) {
            int m = m0 + q * 4 + rr;
            out_bound[(size_t)m * 256 + n_[j]] = facc[j][rr] + bn;
        }
    }

    if (blockIdx.x == 0 && blockIdx.y == 0) {
        float p01 = bacc[0] * (1.f / 2048.f);
        float p02 = bacc[1] * (1.f / 2048.f);
        float p12 = bacc[2] * (1.f / 2048.f);
        float total = (p01 + p02 + p12) * (1.f / 3.f);
        if (t == 0) {
            out_bm[0] = 1.f; out_bm[1] = p01; out_bm[2] = p02;
            out_bm[3] = p01; out_bm[4] = 1.f; out_bm[5] = p12;
            out_bm[6] = p02; out_bm[7] = p12; out_bm[8] = 1.f;
        }
        for (int i = t; i < 2048; i += 256) out_total[i] = total;
    }
}

// ============================ launch ============================
extern "C" void kernel_launch(void* const* d_in, const int* in_sizes, int n_in,
                              void* d_out, int out_size, void* d_ws, size_t ws_size,
                              hipStream_t stream)
{
    const float* x_a  = (const float*)d_in[0];
    const float* Wf_a = (const float*)d_in[1];
    const float* bf_a = (const float*)d_in[2];
    const float* Wp_a = (const float*)d_in[3];
    const float* bp_a = (const float*)d_in[4];
    const float* x_t  = (const float*)d_in[5];
    const float* Wf_t = (const float*)d_in[6];
    const float* bf_t = (const float*)d_in[7];
    const float* Wp_t = (const float*)d_in[8];
    const float* bp_t = (const float*)d_in[9];
    const float* x_v  = (const float*)d_in[10];
    const float* Wf_v = (const float*)d_in[11];
    const float* bf_v = (const float*)d_in[12];
    const float* Wp_v = (const float*)d_in[13];
    const float* bp_v = (const float*)d_in[14];
    const float* om_a = (const float*)d_in[15];
    const float* om_t = (const float*)d_in[16];
    const float* om_v = (const float*)d_in[17];
    const float* IC   = (const float*)d_in[18];
    const float* Wfu  = (const float*)d_in[19];
    const float* bfu  = (const float*)d_in[20];

    float* ws      = (float*)d_ws;
    float* omw     = ws;                        // 256
    float* bpw     = ws + 256;                  // 256
    float* pmv     = ws + 512;                  // 6144
    float* baccw   = ws + 6656;                 // 64
    float* partial = ws + 6720;                 // 128*18*1024 = 2359296
    short* e_bf    = (short*)(ws + 2366016);    // 1572864 shorts
    short* XB      = (short*)(ws + 3152448);    // 4718592 shorts
    short* Kpck    = (short*)(ws + 5511744);    // 36864 shorts
    short* WB      = (short*)(ws + 5530176);    // 786432 shorts

    float* out        = (float*)d_out;
    float* out_bound  = out;           // 2048*256
    float* out_bm     = out + 524288;  // 9
    float* out_phases = out + 524297;  // 2048*192
    float* out_total  = out + 917513;  // 2048

    front_kernel<<<633, 256, 0, stream>>>(
        x_a, x_t, x_v, Wp_a, Wp_t, Wp_v, Wf_a, Wf_t, Wf_v, Wfu,
        IC, om_a, om_t, om_v, bp_a, bp_t, bp_v,
        partial, XB, WB, Kpck, omw, bpw, baccw);

    mid_kernel<<<512, 256, 0, stream>>>(
        XB, WB, bf_a, bf_t, bf_v,
        partial, bpw, Kpck, omw,
        e_bf, out_phases, pmv, baccw);

    dim3 gF(128, 2);
    back_kernel<<<gF, 256, 0, stream>>>(e_bf, WB, bfu, pmv, baccw,
                                        out_bound, out_bm, out_total);
}